// Round 6
// baseline (332.113 us; speedup 1.0000x reference)
//
#include <hip/hip_runtime.h>
#include <stdint.h>
#include <stddef.h>

// Problem constants (B=4, L=1024, D=768, H=6, DH=128)
#define BB 4
#define LL 1024
#define DD 768
#define HH 6
#define DHH 128
#define EPS 1e-5f

// Inputs fp32, outputs fp32.
// Output layout (fp32 elements, concatenated in return order):
//   co : (B,H,L,L) = 25165824
//   w  : (B,L,1)   = 4096
//   Vh : (B,H,L,DH)= 3145728
#define CO_ELEMS 25165824
#define W_ELEMS  4096

// ws layout (fp32 elements), ~6.65 MB total. All deterministic writes.
#define OFF_Q2   0          // 24576
#define OFF_K2   24576      // 24576
#define OFF_SUM  49152      // 48*260: per (which*24+bh): sv[128], tv[128], s2, s22
#define OFF_AC   62000      // a1[8], c1[8]
#define OFF_GD   62016      // gdot[24]
#define OFF_GRAM 65536      // 48*16384
#define OFF_WP   851968     // 32*24*1024 col-sum strip partials
#define OFF_WC   1638400    // 24576 final col sums   (end 1662976 floats)

typedef __attribute__((ext_vector_type(8))) short short8;
typedef __attribute__((ext_vector_type(4))) float f32x4;

// load 8 contiguous fp32, truncate to bf16 fragment
__device__ __forceinline__ short8 ld_bf8(const float* __restrict__ p) {
    const float4 a = *(const float4*)(p);
    const float4 b = *(const float4*)(p + 4);
    short8 r;
    r[0] = (short)(__float_as_uint(a.x) >> 16);
    r[1] = (short)(__float_as_uint(a.y) >> 16);
    r[2] = (short)(__float_as_uint(a.z) >> 16);
    r[3] = (short)(__float_as_uint(a.w) >> 16);
    r[4] = (short)(__float_as_uint(b.x) >> 16);
    r[5] = (short)(__float_as_uint(b.y) >> 16);
    r[6] = (short)(__float_as_uint(b.z) >> 16);
    r[7] = (short)(__float_as_uint(b.w) >> 16);
    return r;
}

// ------------------------------------------------- q2 / k2 (row sq-norms)
__global__ void k_rownorm(const float* __restrict__ Q,
                          const float* __restrict__ K,
                          float* __restrict__ ws) {
    int gid = blockIdx.x * 256 + threadIdx.x;       // 196608
    int sub = gid & 3;
    int rg  = gid >> 2;
    int which = (rg >= 24576);
    int rid = which ? rg - 24576 : rg;              // bh*1024 + i
    int bh = rid >> 10, i = rid & 1023;
    int b = bh / HH, h = bh - b * HH;
    const float* src = (which ? K : Q) + (size_t)(b * LL + i) * DD + h * DHH;
    float s = 0.f;
#pragma unroll
    for (int kk = 0; kk < 8; kk++) {
        float4 v = *(const float4*)(src + (sub + 4 * kk) * 4);
        s += v.x * v.x + v.y * v.y + v.z * v.z + v.w * v.w;
    }
    s += __shfl_xor(s, 1);
    s += __shfl_xor(s, 2);
    if (sub == 0) ws[(which ? OFF_K2 : OFF_Q2) + rid] = s;
}

// ------------------------------------------------- Vh output (exact copy)
__global__ void k_vh(const float* __restrict__ V, float* __restrict__ out) {
    int cid = blockIdx.x * 256 + threadIdx.x;       // 786432 float4 chunks
    if (cid >= 786432) return;
    int d4 = cid & 31;
    int rest = cid >> 5;
    int l = rest & 1023;
    int bh = rest >> 10;
    int b = bh / HH, h = bh - b * HH;
    float4 v = *(const float4*)(V + (size_t)(b * LL + l) * DD + h * DHH + d4 * 4);
    *(float4*)(out + (size_t)cid * 4) = v;
}

// ---- per (b,h,which): sv[d]=Σ_l x[l][d]; tv[d]=Σ_l x2_l x[l][d]; s2; s22
__global__ __launch_bounds__(256) void k_sums(
        const float* __restrict__ Q, const float* __restrict__ Km,
        const float* __restrict__ ws, float* __restrict__ sums) {
    const int bh = blockIdx.x, which = blockIdx.y;
    const int b = bh / HH, h = bh - b * HH;
    const float* X  = (which ? Km : Q) + (size_t)b * LL * DD + h * DHH;
    const float* x2 = ws + (which ? OFF_K2 : OFF_Q2) + bh * 1024;
    const int t = threadIdx.x;
    const int d = t & 127, half = t >> 7;
    float sv = 0.f, tv = 0.f;
#pragma unroll 8
    for (int l = half * 512; l < half * 512 + 512; l++) {
        float x = X[(size_t)l * DD + d];
        float w2 = x2[l];
        sv += x; tv += w2 * x;
    }
    __shared__ float svs[2][128], tvs[2][128], sc[4][2];
    svs[half][d] = sv; tvs[half][d] = tv;
    float s2 = 0.f, s22 = 0.f;
    for (int l = t; l < 1024; l += 256) { float w2 = x2[l]; s2 += w2; s22 += w2 * w2; }
#pragma unroll
    for (int off = 1; off < 64; off <<= 1) { s2 += __shfl_xor(s2, off); s22 += __shfl_xor(s22, off); }
    if ((t & 63) == 0) { sc[t >> 6][0] = s2; sc[t >> 6][1] = s22; }
    __syncthreads();
    float* out = sums + (size_t)(which * 24 + bh) * 260;
    if (t < 128) out[t] = svs[0][t] + svs[1][t];
    else out[t] = tvs[0][t - 128] + tvs[1][t - 128];
    if (t == 0) out[256] = sc[0][0] + sc[1][0] + sc[2][0] + sc[3][0];
    if (t == 1) out[257] = sc[0][1] + sc[1][1] + sc[2][1] + sc[3][1];
}

// ---- per (b,h,which): Gram G = X^T X (128x128) via MFMA from LDS
__global__ __launch_bounds__(256) void k_gram(
        const float* __restrict__ Q, const float* __restrict__ Km,
        float* __restrict__ gram) {
    const int bh = blockIdx.x, which = blockIdx.y;
    const int b = bh / HH, h = bh - b * HH;
    const float* X = (which ? Km : Q) + (size_t)b * LL * DD + h * DHH;
    const int tid = threadIdx.x, lane = tid & 63, wave = tid >> 6;
    const int lm = lane & 15, quad = lane >> 4;
    const int m0 = (wave >> 1) * 64, n0 = (wave & 1) * 64;
    __shared__ float xs[32 * 132];
    f32x4 acc[4][4];
#pragma unroll
    for (int mi = 0; mi < 4; mi++)
#pragma unroll
        for (int ni = 0; ni < 4; ni++) acc[mi][ni] = (f32x4)(0.0f);

    for (int kc = 0; kc < 32; kc++) {
        __syncthreads();
#pragma unroll
        for (int s = 0; s < 4; s++) {
            int fidx = s * 256 + tid;
            int row = fidx >> 5, c4 = fidx & 31;
            float4 v = *(const float4*)(X + (size_t)(kc * 32 + row) * DD + c4 * 4);
            *(float4*)&xs[row * 132 + c4 * 4] = v;
        }
        __syncthreads();
        short8 am[4], bn[4];
#pragma unroll
        for (int mi = 0; mi < 4; mi++) {
            short8 f;
#pragma unroll
            for (int j = 0; j < 8; j++) {
                float v = xs[(quad * 8 + j) * 132 + m0 + mi * 16 + lm];
                f[j] = (short)(__float_as_uint(v) >> 16);
            }
            am[mi] = f;
        }
#pragma unroll
        for (int ni = 0; ni < 4; ni++) {
            short8 f;
#pragma unroll
            for (int j = 0; j < 8; j++) {
                float v = xs[(quad * 8 + j) * 132 + n0 + ni * 16 + lm];
                f[j] = (short)(__float_as_uint(v) >> 16);
            }
            bn[ni] = f;
        }
#pragma unroll
        for (int mi = 0; mi < 4; mi++)
#pragma unroll
            for (int ni = 0; ni < 4; ni++)
                acc[mi][ni] = __builtin_amdgcn_mfma_f32_16x16x32_bf16(am[mi], bn[ni], acc[mi][ni], 0, 0, 0);
    }
    float* G = gram + (size_t)(which * 24 + bh) * 16384;
#pragma unroll
    for (int mi = 0; mi < 4; mi++)
#pragma unroll
        for (int ni = 0; ni < 4; ni++)
#pragma unroll
            for (int r = 0; r < 4; r++)
                G[(m0 + mi * 16 + quad * 4 + r) * 128 + (n0 + ni * 16 + lm)] = acc[mi][ni][r];
}

// ---- per bh: <G_q, G_k> Frobenius dot
__global__ void k_gramdot(const float* __restrict__ gram, float* __restrict__ gd) {
    const int bh = blockIdx.x, t = threadIdx.x;
    const float* Gq = gram + (size_t)bh * 16384;
    const float* Gk = gram + (size_t)(24 + bh) * 16384;
    float s = 0.f;
    for (int i = t; i < 16384; i += 256) s += Gq[i] * Gk[i];
#pragma unroll
    for (int off = 1; off < 64; off <<= 1) s += __shfl_xor(s, off);
    __shared__ float sc[4];
    if ((t & 63) == 0) sc[t >> 6] = s;
    __syncthreads();
    if (t == 0) gd[bh] = sc[0] + sc[1] + sc[2] + sc[3];
}

// ---- closed-form batchnorm stats -> a1, c1 per head
__global__ void k_stats2(const float* __restrict__ sums, const float* __restrict__ gd,
                         const float* __restrict__ g1, const float* __restrict__ b1,
                         float* __restrict__ ac) {
    const int t = threadIdx.x;
    __shared__ double sA[24], sB[24];
    if (t < 24) {
        const float* sq_ = sums + (size_t)t * 260;
        const float* sk_ = sums + (size_t)(24 + t) * 260;
        double dqk = 0, dtqk = 0, dtkq = 0;
        for (int d = 0; d < 128; d++) {
            dqk  += (double)sq_[d] * sk_[d];
            dtqk += (double)sq_[128 + d] * sk_[d];        // (Σ q2 q)·Sk
            dtkq += (double)sk_[128 + d] * sq_[d];        // (Σ k2 k)·Sq
        }
        double s2q = sq_[256], s22q = sq_[257];
        double s2k = sk_[256], s22k = sk_[257];
        sA[t] = -1024.0 * (s2q + s2k) + 2.0 * dqk;
        sB[t] = 1024.0 * (s22q + s22k) + 4.0 * (double)gd[t]
              + 2.0 * s2q * s2k - 4.0 * dtqk - 4.0 * dtkq;
    }
    __syncthreads();
    if (t < HH) {
        double hs = 0, hq = 0;
        for (int b = 0; b < 4; b++) { hs += sA[b * HH + t]; hq += sB[b * HH + t]; }
        const double N = 4194304.0;
        double m = hs / N;
        double var = hq / N - m * m;
        if (var < 0) var = 0;
        float r = rsqrtf((float)var + EPS);
        float a = r * g1[t];
        ac[t] = a;
        ac[8 + t] = b1[t] - (float)m * a;
    }
}

// ---- THE fused pass: GEMM full-row strip -> BN -> mask -> exp -> row
// softmax (cross-wave LDS) -> write final p once; col-sum strip partials.
// Block: 4 waves, 32 rows x 1024 cols; wave owns 32x256 (acc[2][16]).
__global__ __launch_bounds__(256, 2) void k_fused(
        const float* __restrict__ Q, const float* __restrict__ Km,
        const float* __restrict__ q2, const float* __restrict__ k2,
        const float* __restrict__ ac, const unsigned char* __restrict__ bx,
        float* __restrict__ co, float* __restrict__ wcolP) {
    const int strip = blockIdx.x;         // 32 strips of 32 rows
    const int bh = blockIdx.y;            // 24
    const int b = bh / HH, h = bh - b * HH;
    const int tid = threadIdx.x, lane = tid & 63, wave = tid >> 6;
    const int lm = lane & 15, quad = lane >> 4;
    const int ibase = strip * 32;
    const int colbase = wave * 256;
    const float* Qb = Q + (size_t)b * LL * DD + h * DHH;
    const float* Kb = Km + (size_t)b * LL * DD + h * DHH;

    f32x4 acc[2][16];
#pragma unroll
    for (int ti = 0; ti < 2; ti++)
#pragma unroll
        for (int tj = 0; tj < 16; tj++) acc[ti][tj] = (f32x4)(0.0f);

#pragma unroll
    for (int kk = 0; kk < 4; kk++) {
        const int d0 = kk * 32 + quad * 8;
        short8 af0 = ld_bf8(Qb + (size_t)(ibase + lm) * DD + d0);
        short8 af1 = ld_bf8(Qb + (size_t)(ibase + 16 + lm) * DD + d0);
#pragma unroll
        for (int tj = 0; tj < 16; tj++) {
            short8 bf = ld_bf8(Kb + (size_t)(colbase + tj * 16 + lm) * DD + d0);
            acc[0][tj] = __builtin_amdgcn_mfma_f32_16x16x32_bf16(af0, bf, acc[0][tj], 0, 0, 0);
            acc[1][tj] = __builtin_amdgcn_mfma_f32_16x16x32_bf16(af1, bf, acc[1][tj], 0, 0, 0);
        }
    }

    const float a = ac[h], c = ac[8 + h];
    const unsigned char* bxb = bx + b * LL;
    float q2v[8]; bool vi[8];
#pragma unroll
    for (int ti = 0; ti < 2; ti++)
#pragma unroll
        for (int r = 0; r < 4; r++) {
            int i = ibase + ti * 16 + quad * 4 + r;
            q2v[ti * 4 + r] = q2[bh * 1024 + i];
            vi[ti * 4 + r] = (bxb[i] == 0);
        }
    float k2v[16]; bool vj[16];
#pragma unroll
    for (int tj = 0; tj < 16; tj++) {
        int j = colbase + tj * 16 + lm;
        k2v[tj] = k2[bh * 1024 + j];
        vj[tj] = (bxb[j] == 0);
    }

    float rp[8] = {0.f, 0.f, 0.f, 0.f, 0.f, 0.f, 0.f, 0.f};
#pragma unroll
    for (int ti = 0; ti < 2; ti++)
#pragma unroll
        for (int tj = 0; tj < 16; tj++)
#pragma unroll
            for (int r = 0; r < 4; r++) {
                float S = 2.0f * acc[ti][tj][r] - q2v[ti * 4 + r] - k2v[tj];
                float z = (vi[ti * 4 + r] && vj[tj]) ? fminf(a * S + c, 60.0f) : 0.0f;
                float e = __expf(z);
                acc[ti][tj][r] = e;
                rp[ti * 4 + r] += e;
            }

    // row sums: reduce over the 16 col-lanes, then cross-wave via LDS
#pragma unroll
    for (int u = 0; u < 8; u++) {
        rp[u] += __shfl_xor(rp[u], 1);
        rp[u] += __shfl_xor(rp[u], 2);
        rp[u] += __shfl_xor(rp[u], 4);
        rp[u] += __shfl_xor(rp[u], 8);
    }
    __shared__ float rs[32][5];
    __shared__ float invs[32];
    __shared__ float colsum[1024];
    if (lm == 0) {
#pragma unroll
        for (int ti = 0; ti < 2; ti++)
#pragma unroll
            for (int r = 0; r < 4; r++)
                rs[ti * 16 + quad * 4 + r][wave] = rp[ti * 4 + r];
    }
    __syncthreads();
    if (tid < 32) invs[tid] = 1.0f / (rs[tid][0] + rs[tid][1] + rs[tid][2] + rs[tid][3]);
    __syncthreads();
    float iv[8];
#pragma unroll
    for (int ti = 0; ti < 2; ti++)
#pragma unroll
        for (int r = 0; r < 4; r++) iv[ti * 4 + r] = invs[ti * 16 + quad * 4 + r];

    float cs[16];
#pragma unroll
    for (int tj = 0; tj < 16; tj++) cs[tj] = 0.f;
#pragma unroll
    for (int ti = 0; ti < 2; ti++)
#pragma unroll
        for (int tj = 0; tj < 16; tj++)
#pragma unroll
            for (int r = 0; r < 4; r++) {
                float p = acc[ti][tj][r] * iv[ti * 4 + r];
                acc[ti][tj][r] = p;
                cs[tj] += p;
            }

    // write p (scattered dword; 64B segments -> no write amplification, r5)
    float* cob = co + ((size_t)bh << 20);
#pragma unroll
    for (int ti = 0; ti < 2; ti++)
#pragma unroll
        for (int tj = 0; tj < 16; tj++)
#pragma unroll
            for (int r = 0; r < 4; r++) {
                int i = ibase + ti * 16 + quad * 4 + r;
                int j = colbase + tj * 16 + lm;
                cob[((size_t)i << 10) + j] = acc[ti][tj][r];
            }

    // col sums across the 4 quads, then strip partial out
#pragma unroll
    for (int tj = 0; tj < 16; tj++) {
        cs[tj] += __shfl_xor(cs[tj], 16);
        cs[tj] += __shfl_xor(cs[tj], 32);
    }
    if (quad == 0) {
#pragma unroll
        for (int tj = 0; tj < 16; tj++) colsum[colbase + tj * 16 + lm] = cs[tj];
    }
    __syncthreads();
    float4 wv = *(const float4*)&colsum[tid * 4];
    *(float4*)&wcolP[((size_t)strip * 24 + bh) * 1024 + tid * 4] = wv;
}

// ---- reduce col-sum strip partials -> wcol (B*H, L)
__global__ void k_wcol_reduce(const float* __restrict__ wcolP,
                              float* __restrict__ wcol) {
    int g = blockIdx.x * 256 + threadIdx.x;          // 24576
    if (g >= 24576) return;
    float s = 0.f;
#pragma unroll 8
    for (int strip = 0; strip < 32; strip++)
        s += wcolP[(size_t)strip * 24576 + g];
    wcol[g] = s;
}

// ------- tail: norm2 + gate + per-batch softmax (shuffle reductions)
__global__ __launch_bounds__(1024) void k_tail(
        const float* __restrict__ wcol, const unsigned char* __restrict__ bx,
        const float* __restrict__ g2, const float* __restrict__ b2,
        const float* __restrict__ Wp, const float* __restrict__ bp,
        float* __restrict__ wout) {
    const int t = threadIdx.x, lane = t & 63, wv = t >> 6;
    __shared__ float lds1[16][12];
    __shared__ float tmp12[12];
    __shared__ float abuf[12];       // a2s[0..5], c2s[6..11]
    __shared__ float xb[4096];
    __shared__ float wred[16][2];

    float s[HH], s2[HH];
#pragma unroll
    for (int h = 0; h < HH; h++) { s[h] = 0.f; s2[h] = 0.f; }
#pragma unroll
    for (int p = 0; p < 4; p++) {
        int idx = t + p * 1024;
        int b = idx >> 10, l = idx & 1023;
#pragma unroll
        for (int h = 0; h < HH; h++) {
            float v = wcol[(size_t)(b * HH + h) * 1024 + l];
            s[h] += v; s2[h] += v * v;
        }
    }
#pragma unroll
    for (int h = 0; h < HH; h++)
#pragma unroll
        for (int off = 1; off < 64; off <<= 1) {
            s[h] += __shfl_xor(s[h], off);
            s2[h] += __shfl_xor(s2[h], off);
        }
    if (lane == 0) {
#pragma unroll
        for (int h = 0; h < HH; h++) { lds1[wv][h] = s[h]; lds1[wv][6 + h] = s2[h]; }
    }
    __syncthreads();
    if (t < 12) {
        float acc = 0.f;
#pragma unroll
        for (int w = 0; w < 16; w++) acc += lds1[w][t];
        tmp12[t] = acc;
    }
    __syncthreads();
    if (t < HH) {
        float m = tmp12[t] / 4096.f;
        float var = fmaxf(tmp12[6 + t] / 4096.f - m * m, 0.0f);
        float r = rsqrtf(var + EPS);
        float a = r * g2[t];
        abuf[t] = a;
        abuf[6 + t] = b2[t] - m * a;
    }
    __syncthreads();

    const float bp0 = bp[0], bp1 = bp[1];
#pragma unroll
    for (int p = 0; p < 4; p++) {
        int idx = t + p * 1024;
        int b = idx >> 10, l = idx & 1023;
        float z0 = bp0, z1 = bp1;
#pragma unroll
        for (int h = 0; h < HH; h++) {
            float wn = abuf[h] * wcol[(size_t)(b * HH + h) * 1024 + l] + abuf[6 + h];
            z0 += wn * Wp[h];
            z1 += wn * Wp[HH + h];
        }
        float pc = 1.0f / (1.0f + __expf(z1 - z0));
        xb[idx] = bx[b * LL + l] ? -INFINITY : pc;
    }
    __syncthreads();

    // per-batch softmax: 4 waves per batch, thread owns 4 elems
    const int bb = t >> 8, tb = t & 255;
    float4 xv = *(const float4*)&xb[bb * 1024 + tb * 4];
    float mx = fmaxf(fmaxf(xv.x, xv.y), fmaxf(xv.z, xv.w));
#pragma unroll
    for (int off = 1; off < 64; off <<= 1) mx = fmaxf(mx, __shfl_xor(mx, off));
    if (lane == 0) wred[wv][0] = mx;
    __syncthreads();
    mx = fmaxf(fmaxf(wred[bb * 4][0], wred[bb * 4 + 1][0]),
               fmaxf(wred[bb * 4 + 2][0], wred[bb * 4 + 3][0]));
    float e0 = __expf(xv.x - mx), e1 = __expf(xv.y - mx);
    float e2 = __expf(xv.z - mx), e3 = __expf(xv.w - mx);
    float ss = e0 + e1 + e2 + e3;
#pragma unroll
    for (int off = 1; off < 64; off <<= 1) ss += __shfl_xor(ss, off);
    if (lane == 0) wred[wv][1] = ss;
    __syncthreads();
    float sum = wred[bb * 4][1] + wred[bb * 4 + 1][1] + wred[bb * 4 + 2][1] + wred[bb * 4 + 3][1];
    float4 o;
    o.x = e0 / sum; o.y = e1 / sum; o.z = e2 / sum; o.w = e3 / sum;
    *(float4*)&wout[bb * 1024 + tb * 4] = o;
}

extern "C" void kernel_launch(void* const* d_in, const int* in_sizes, int n_in,
                              void* d_out, int out_size, void* d_ws, size_t ws_size,
                              hipStream_t stream) {
    const float* Q  = (const float*)d_in[0];
    const float* K  = (const float*)d_in[1];
    const float* V  = (const float*)d_in[2];
    // d_in[3] = pad_mask (B,L,L) — derivable from bx_packed, unused
    const unsigned char* bx = (const unsigned char*)d_in[4];
    const float* g1 = (const float*)d_in[5];
    const float* b1 = (const float*)d_in[6];
    const float* g2 = (const float*)d_in[7];
    const float* b2 = (const float*)d_in[8];
    const float* Wp = (const float*)d_in[9];
    const float* bp = (const float*)d_in[10];

    float* out  = (float*)d_out;
    float* co   = out;                        // (B,H,L,L)
    float* wout = out + CO_ELEMS;             // (B,L,1)
    float* vh   = out + CO_ELEMS + W_ELEMS;   // (B,H,L,DH)

    float* ws = (float*)d_ws;                 // ~6.65 MB
    float* q2    = ws + OFF_Q2;
    float* k2    = ws + OFF_K2;
    float* sums  = ws + OFF_SUM;
    float* ac    = ws + OFF_AC;
    float* gd    = ws + OFF_GD;
    float* gram  = ws + OFF_GRAM;
    float* wcolP = ws + OFF_WP;
    float* wcol  = ws + OFF_WC;

    k_rownorm<<<768, 256, 0, stream>>>(Q, K, ws);
    k_vh<<<3072, 256, 0, stream>>>(V, vh);
    k_sums<<<dim3(24, 2), 256, 0, stream>>>(Q, K, ws, sums);
    k_gram<<<dim3(24, 2), 256, 0, stream>>>(Q, K, gram);
    k_gramdot<<<24, 256, 0, stream>>>(gram, gd);
    k_stats2<<<1, 64, 0, stream>>>(sums, gd, g1, b1, ac);
    k_fused<<<dim3(32, 24), 256, 0, stream>>>(Q, K, q2, k2, ac, bx, co, wcolP);
    k_wcol_reduce<<<96, 256, 0, stream>>>(wcolP, wcol);
    k_tail<<<1, 1024, 0, stream>>>(wcol, bx, g2, b2, Wp, bp, wout);
}